// Round 11
// baseline (295.090 us; speedup 1.0000x reference)
//
#include <hip/hip_runtime.h>
#include <math.h>

#define DIMC 128
#define LSEQ 12288
#define NB 2
#define BLR 24576   // NB*LSEQ
#define EPSV 1e-5f
#define NCH 512     // scan chunks per row (4096 blocks -> full wave capacity)
#define LC 24       // chunk length (NCH*LC = LSEQ)
#define KP 132      // LDS row pad (ushorts) for MFMA staging

typedef __bf16 bf16x8 __attribute__((ext_vector_type(8)));
typedef __attribute__((ext_vector_type(4))) float f4_t;

__device__ __forceinline__ float sigf(float x){ return 1.f/(1.f+__expf(-x)); }
__device__ __forceinline__ float softplusf(float x){
    return fmaxf(x,0.f) + __logf(1.f + __expf(-fabsf(x)));
}
__device__ __forceinline__ float bf2f(unsigned short u){
    union { unsigned int i; float f; } v; v.i = ((unsigned int)u) << 16; return v.f;
}
__device__ __forceinline__ unsigned short f2bf(float f){
    union { float f; unsigned int i; } v; v.f = f;
    unsigned int b = v.i + 0x7FFFu + ((v.i >> 16) & 1u);
    return (unsigned short)(b >> 16);
}
__device__ __forceinline__ bf16x8 ld_frag8(const unsigned short* p){   // 8B-aligned LDS
    union { uint2 u[2]; bf16x8 v; } r;
    r.u[0] = *(const uint2*)(p);
    r.u[1] = *(const uint2*)(p+4);
    return r.v;
}
__device__ __forceinline__ bf16x8 ld_frag16g(const unsigned short* p){ // 16B-aligned global
    union { uint4 u; bf16x8 v; } r; r.u = *(const uint4*)p; return r.v;
}

// ---------------------------------------------------------------- W_all[inst][144][128] (bf16) + lam
__global__ void k_wall(const float* __restrict__ dtw, const float* __restrict__ xpw,
                       const float* __restrict__ lq,
                       unsigned short* __restrict__ wallb, float* __restrict__ lam){
    int inst = blockIdx.x, j = blockIdx.y, k = threadIdx.x;  // grid (4,144), block 128
    const float* xp = xpw + (size_t)inst*24*128;
    float v;
    if (j < 128){
        const float* dw = dtw + (size_t)inst*128*8 + (size_t)j*8;
        v = 0.f;
        #pragma unroll
        for (int r = 0; r < 8; r++) v += dw[r]*xp[r*128 + k];
    } else {
        v = xp[(8 + (j-128))*128 + k];
    }
    wallb[((size_t)inst*144 + j)*128 + k] = f2bf(v);
    if (inst == 0 && j == 0 && k < 64){
        float s = lq[k] + lq[k+64];
        for (int m = 32; m; m >>= 1) s += __shfl_xor(s, m);
        if (k == 0) *lam = 1.f/(1.f+__expf(-s));
    }
}

// ---------------------------------------------------------------- wi, ow -> bf16
__global__ __launch_bounds__(256) void k_prep(const float* __restrict__ wi, const float* __restrict__ ow,
    unsigned short* __restrict__ wib, unsigned short* __restrict__ owb){
    int idx = (blockIdx.x*256 + threadIdx.x)*4;   // grid 96 -> 98304 elems
    const float* src; unsigned short* dst; int off;
    if (idx < 65536){ src = wi;  dst = wib; off = idx; }
    else            { src = ow;  dst = owb; off = idx - 65536; }
    float4 v = *(const float4*)&src[off];
    ushort4 o; o.x=f2bf(v.x); o.y=f2bf(v.y); o.z=f2bf(v.z); o.w=f2bf(v.w);
    *(ushort4*)&dst[off] = o;
}

// ---------------------------------------------------------------- LN1 + transpose -> xn bf16 [b*l][128], 32-row tiles
__global__ __launch_bounds__(256) void k_normT(const float* __restrict__ x,
    const float* __restrict__ w1, const float* __restrict__ b1, unsigned short* __restrict__ xn)
{
    __shared__ float t[32*129];
    __shared__ float red1[256], red2[256];
    __shared__ float stt[64];
    const int bb = blockIdx.x / 384;           // grid = 768
    const int l0 = (blockIdx.x % 384) * 32;
    const int tid = threadIdx.x;
    const int li = tid & 31, cg = tid >> 5;    // 8 col groups
    #pragma unroll
    for (int p = 0; p < 16; p++){
        int c = p*8 + cg;
        t[li*129 + c] = x[(size_t)bb*DIMC*LSEQ + (size_t)c*LSEQ + l0 + li];
    }
    __syncthreads();
    {
        int r = tid >> 3, qg = tid & 7;        // 32 rows, 8 thr/row, 16 cols each
        float s = 0.f, s2 = 0.f;
        #pragma unroll
        for (int j = 0; j < 16; j++){ float v = t[r*129 + qg*16 + j]; s += v; s2 += v*v; }
        red1[qg*32 + r] = s; red2[qg*32 + r] = s2;
    }
    __syncthreads();
    if (tid < 32){
        float s = 0.f, s2 = 0.f;
        #pragma unroll
        for (int g = 0; g < 8; g++){ s += red1[g*32 + tid]; s2 += red2[g*32 + tid]; }
        float mu = s*(1.f/128.f);
        float var = s2*(1.f/128.f) - mu*mu;
        stt[tid*2] = mu; stt[tid*2+1] = rsqrtf(var + EPSV);
    }
    __syncthreads();
    const int c2 = (tid & 63)*2, lg = tid >> 6;
    #pragma unroll
    for (int p = 0; p < 8; p++){
        int l = p*4 + lg;
        float mu = stt[l*2], rs = stt[l*2+1];
        float v0 = (t[l*129 + c2    ] - mu)*rs*w1[c2    ] + b1[c2    ];
        float v1 = (t[l*129 + c2 + 1] - mu)*rs*w1[c2 + 1] + b1[c2 + 1];
        unsigned int o = (unsigned int)f2bf(v0) | ((unsigned int)f2bf(v1) << 16);
        *(unsigned int*)&xn[(size_t)(bb*LSEQ + l0 + l)*DIMC + c2] = o;
    }
}

// ---------------------------------------------------------------- in_proj MFMA: [128m x 128n x 128k] tiles
__global__ __launch_bounds__(256,4) void k_inproj(const unsigned short* __restrict__ xn,
    const unsigned short* __restrict__ wib, unsigned short* __restrict__ xz)
{
    __shared__ __align__(16) unsigned short As[128*KP];   // 33792 B
    const int row0 = blockIdx.x * 128;   // grid.x = 192
    const int j0   = blockIdx.y * 128;   // grid.y = 4
    const int tid = threadIdx.x;
    #pragma unroll
    for (int p = 0; p < 8; p++){
        int idx = p*256 + tid; int li = idx >> 4; int g = (idx & 15)*8;
        uint4 va = *(const uint4*)&xn[(size_t)(row0+li)*DIMC + g];
        *(uint2*)&As[li*KP + g]     = make_uint2(va.x, va.y);
        *(uint2*)&As[li*KP + g + 4] = make_uint2(va.z, va.w);
    }
    __syncthreads();
    const int lane = tid & 63, w = tid >> 6;
    const int m15 = lane & 15, q = lane >> 4;
    f4_t zf = {0.f,0.f,0.f,0.f};
    f4_t acc[2][8];
    #pragma unroll
    for (int i = 0; i < 2; i++)
        #pragma unroll
        for (int j = 0; j < 8; j++) acc[i][j] = zf;
    #pragma unroll
    for (int ks = 0; ks < 4; ks++){
        int k0 = ks*32 + q*8;
        bf16x8 a0 = ld_frag8(&As[(w*32      + m15)*KP + k0]);
        bf16x8 a1 = ld_frag8(&As[(w*32 + 16 + m15)*KP + k0]);
        #pragma unroll
        for (int nt = 0; nt < 8; nt++){
            bf16x8 b = ld_frag16g(&wib[(size_t)(j0 + nt*16 + m15)*DIMC + k0]);
            acc[0][nt] = __builtin_amdgcn_mfma_f32_16x16x32_bf16(a0, b, acc[0][nt], 0,0,0);
            acc[1][nt] = __builtin_amdgcn_mfma_f32_16x16x32_bf16(a1, b, acc[1][nt], 0,0,0);
        }
    }
    __syncthreads();
    unsigned short* ep = As;             // reuse
    #pragma unroll
    for (int mi = 0; mi < 2; mi++)
        #pragma unroll
        for (int nt = 0; nt < 8; nt++){
            int row = w*32 + mi*16 + q*4;
            int col = nt*16 + m15;
            #pragma unroll
            for (int i = 0; i < 4; i++)
                ep[(row+i)*KP + col] = f2bf(acc[mi][nt][i]);
        }
    __syncthreads();
    #pragma unroll
    for (int p = 0; p < 8; p++){
        int idx = p*256 + tid; int li = idx >> 4; int g = (idx & 15)*8;
        uint2 u0 = *(const uint2*)&ep[li*KP + g];
        uint2 u1 = *(const uint2*)&ep[li*KP + g + 4];
        uint4 o; o.x=u0.x; o.y=u0.y; o.z=u1.x; o.w=u1.y;
        *(uint4*)&xz[(size_t)(row0+li)*512 + j0 + g] = o;
    }
}

// ---------------------------------------------------------------- conv (both directions) + silu
__global__ __launch_bounds__(256) void k_conv(const unsigned short* __restrict__ xz,
    const float* __restrict__ cw, const float* __restrict__ cb, unsigned short* __restrict__ xc)
{
    __shared__ unsigned short tile[70][144];
    const int bid = blockIdx.x;                // grid = 2*2*192
    const int lt = bid % 192;
    const int bb = (bid/192) % NB;
    const int m  = bid / (192*NB);
    const int l0 = lt * 64;
    const int tid = threadIdx.x;
    for (int idx = tid; idx < 70*16; idx += 256){
        int r = idx >> 4, cq = idx & 15;
        int l = l0 - 3 + r;
        uint4 v = make_uint4(0,0,0,0);
        if (l >= 0 && l < LSEQ)
            v = *(const uint4*)&xz[((size_t)(bb*LSEQ + l))*512 + m*256 + cq*8];
        *(uint4*)&tile[r][cq*8] = v;
    }
    __syncthreads();
    const int dimi = tid & 127, lg = tid >> 7;
    float w0a[4], w1a[4];
    #pragma unroll
    for (int k = 0; k < 4; k++){
        w0a[k] = cw[((size_t)(m*2+0)*DIMC + dimi)*4 + k];
        w1a[k] = cw[((size_t)(m*2+1)*DIMC + dimi)*4 + k];
    }
    const float b0 = cb[(m*2+0)*DIMC + dimi];
    const float b1v = cb[(m*2+1)*DIMC + dimi];
    for (int p = 0; p < 32; p++){
        int li = p*2 + lg;
        float t0 = bf2f(tile[li  ][dimi]);
        float t1 = bf2f(tile[li+1][dimi]);
        float t2 = bf2f(tile[li+2][dimi]);
        float t3 = bf2f(tile[li+3][dimi]);
        float t4 = bf2f(tile[li+4][dimi]);
        float t5 = bf2f(tile[li+5][dimi]);
        float t6 = bf2f(tile[li+6][dimi]);
        float v0 = b0  + w0a[0]*t0 + w0a[1]*t1 + w0a[2]*t2 + w0a[3]*t3;
        float v1 = b1v + w1a[3]*t3 + w1a[2]*t4 + w1a[1]*t5 + w1a[0]*t6;
        v0 = v0 * sigf(v0);
        v1 = v1 * sigf(v1);
        xc[(((size_t)(m*2+0)*NB + bb)*LSEQ + l0 + li)*DIMC + dimi] = f2bf(v0);
        xc[(((size_t)(m*2+1)*NB + bb)*LSEQ + l0 + li)*DIMC + dimi] = f2bf(v1);
    }
}

// ---------------------------------------------------------------- x_proj MFMA: [128m x 144n x 128k] per ib
__global__ __launch_bounds__(256,4) void k_xproj(const unsigned short* __restrict__ xc,
    const unsigned short* __restrict__ wallb, const float* __restrict__ dtb,
    unsigned short* __restrict__ dty, float* __restrict__ bcb)
{
    __shared__ __align__(16) unsigned short As[128*KP];   // 33792 B
    const int row0 = blockIdx.x * 128;   // grid.x = 96
    const int ib   = blockIdx.y;         // 0..7
    const int inst = ib >> 1;
    const int tid = threadIdx.x;
    const size_t abase = (size_t)ib * LSEQ * DIMC;
    #pragma unroll
    for (int p = 0; p < 8; p++){
        int idx = p*256 + tid; int li = idx >> 4; int g = (idx & 15)*8;
        uint4 va = *(const uint4*)&xc[abase + (size_t)(row0+li)*DIMC + g];
        *(uint2*)&As[li*KP + g]     = make_uint2(va.x, va.y);
        *(uint2*)&As[li*KP + g + 4] = make_uint2(va.z, va.w);
    }
    __syncthreads();
    const int lane = tid & 63, w = tid >> 6;
    const int m15 = lane & 15, q = lane >> 4;
    f4_t zf = {0.f,0.f,0.f,0.f};
    f4_t acc[2][9];
    #pragma unroll
    for (int i = 0; i < 2; i++)
        #pragma unroll
        for (int j = 0; j < 9; j++) acc[i][j] = zf;
    #pragma unroll
    for (int ks = 0; ks < 4; ks++){
        int k0 = ks*32 + q*8;
        bf16x8 a0 = ld_frag8(&As[(w*32      + m15)*KP + k0]);
        bf16x8 a1 = ld_frag8(&As[(w*32 + 16 + m15)*KP + k0]);
        #pragma unroll
        for (int nt = 0; nt < 9; nt++){
            bf16x8 b = ld_frag16g(&wallb[((size_t)inst*144 + nt*16 + m15)*DIMC + k0]);
            acc[0][nt] = __builtin_amdgcn_mfma_f32_16x16x32_bf16(a0, b, acc[0][nt], 0,0,0);
            acc[1][nt] = __builtin_amdgcn_mfma_f32_16x16x32_bf16(a1, b, acc[1][nt], 0,0,0);
        }
    }
    #pragma unroll
    for (int mi = 0; mi < 2; mi++){
        int row = w*32 + mi*16 + q*4;
        #pragma unroll
        for (int i = 0; i < 4; i++)
            bcb[((size_t)ib*LSEQ + row0 + row + i)*16 + m15] = acc[mi][8][i];
    }
    __syncthreads();
    unsigned short* ep = As;             // dt bf16 [128][KP]
    #pragma unroll
    for (int nt = 0; nt < 8; nt++){
        int col = nt*16 + m15;
        float bias = dtb[inst*DIMC + col];
        #pragma unroll
        for (int mi = 0; mi < 2; mi++){
            int row = w*32 + mi*16 + q*4;
            #pragma unroll
            for (int i = 0; i < 4; i++)
                ep[(row+i)*KP + col] = f2bf(softplusf(acc[mi][nt][i] + bias));
        }
    }
    __syncthreads();
    #pragma unroll
    for (int p = 0; p < 8; p++){
        int idx = p*256 + tid; int li = idx >> 4; int g = (idx & 15)*8;
        uint2 u0 = *(const uint2*)&ep[li*KP + g];
        uint2 u1 = *(const uint2*)&ep[li*KP + g + 4];
        uint4 o; o.x=u0.x; o.y=u0.y; o.z=u1.x; o.w=u1.y;
        *(uint4*)&dty[abase + (size_t)(row0+li)*DIMC + g] = o;
    }
}

// ---------------------------------------------------------------- scan S1 (per-chunk reduce)
__global__ __launch_bounds__(128) void k_scan1(const unsigned short* __restrict__ dt,
    const unsigned short* __restrict__ xc, const float* __restrict__ bcb,
    const float* __restrict__ alog, float* __restrict__ st)
{
    const int ib = blockIdx.x & 7;
    const int c  = blockIdx.x >> 3;            // 0..NCH-1
    const int inst = ib >> 1;
    const int d = inst & 1;
    const int tid = threadIdx.x;
    float Av[8];
    #pragma unroll
    for (int n = 0; n < 8; n++)
        Av[n] = -__expf(alog[((size_t)inst*DIMC + tid)*8 + n]);
    const int l0i = d ? (LSEQ-1 - c*LC) : (c*LC);
    const ptrdiff_t step = d ? -1 : 1;
    size_t ro = (size_t)ib*LSEQ*DIMC + (size_t)l0i*DIMC + tid;
    const float* bp = bcb + ((size_t)ib*LSEQ + l0i)*16;
    const ptrdiff_t rostep = step*DIMC;
    const ptrdiff_t bpstep = step*16;
    float Ac[8], Bc[8];
    #pragma unroll
    for (int n = 0; n < 8; n++){ Ac[n] = 1.f; Bc[n] = 0.f; }
    #pragma unroll 4
    for (int s = 0; s < LC; s++){
        float dtv = bf2f(dt[ro]);
        float uv  = bf2f(xc[ro]);
        float4 bA = *(const float4*)bp;
        float4 bB = *(const float4*)(bp+4);
        float bv[8] = {bA.x,bA.y,bA.z,bA.w,bB.x,bB.y,bB.z,bB.w};
        float du = dtv*uv;
        #pragma unroll
        for (int n = 0; n < 8; n++){
            float a = __expf(dtv*Av[n]);
            Bc[n] = a*Bc[n] + du*bv[n];
            Ac[n] *= a;
        }
        ro += rostep; bp += bpstep;
    }
    float* so = st + (((size_t)ib*NCH + c)*DIMC + tid)*16;
    #pragma unroll
    for (int n = 0; n < 8; n++){ so[n] = Ac[n]; so[8+n] = Bc[n]; }
}

// ---------------------------------------------------------------- scan S2 (cross-chunk exclusive prefix, in-place)
__global__ __launch_bounds__(256) void k_scan2(float* __restrict__ st){
    int gid = blockIdx.x*256 + threadIdx.x;    // 8192 threads
    int ib = gid >> 10;
    int r  = gid & 1023;
    int dim = r >> 3, n = r & 7;
    float Bp = 0.f;
    for (int c = 0; c < NCH; c++){
        size_t o = (((size_t)ib*NCH + c)*DIMC + dim)*16;
        float A = st[o+n], Bv = st[o+8+n];
        st[o+n] = Bp;
        Bp = A*Bp + Bv;
    }
}

// ---------------------------------------------------------------- scan S3 (replay, y in place over dt)
__global__ __launch_bounds__(128) void k_scan3(unsigned short* __restrict__ dty,
    const unsigned short* __restrict__ xc, const float* __restrict__ bcb,
    const unsigned short* __restrict__ xz, const float* __restrict__ st,
    const float* __restrict__ alog, const float* __restrict__ dvec)
{
    const int ib = blockIdx.x & 7;
    const int c  = blockIdx.x >> 3;
    const int inst = ib >> 1, bb = ib & 1;
    const int m = inst >> 1, d = inst & 1;
    const int tid = threadIdx.x;
    float Av[8];
    #pragma unroll
    for (int n = 0; n < 8; n++)
        Av[n] = -__expf(alog[((size_t)inst*DIMC + tid)*8 + n]);
    const float Dv = dvec[inst*DIMC + tid];
    float h[8];
    const float* hp = st + (((size_t)ib*NCH + c)*DIMC + tid)*16;
    #pragma unroll
    for (int n = 0; n < 8; n++) h[n] = hp[n];
    const int l0i = d ? (LSEQ-1 - c*LC) : (c*LC);
    const ptrdiff_t step = d ? -1 : 1;
    size_t ro = (size_t)ib*LSEQ*DIMC + (size_t)l0i*DIMC + tid;
    const float* bp = bcb + ((size_t)ib*LSEQ + l0i)*16;
    const unsigned short* zp = xz + (size_t)bb*LSEQ*512 + m*256 + 128 + (size_t)l0i*512 + tid;
    const ptrdiff_t rostep = step*DIMC;
    const ptrdiff_t bpstep = step*16;
    const ptrdiff_t zpstep = step*512;
    #pragma unroll 4
    for (int s = 0; s < LC; s++){
        float dtv = bf2f(dty[ro]);
        float uv  = bf2f(xc[ro]);
        float4 bA = *(const float4*)bp;
        float4 bB = *(const float4*)(bp+4);
        float4 cA = *(const float4*)(bp+8);
        float4 cB = *(const float4*)(bp+12);
        float bv[8] = {bA.x,bA.y,bA.z,bA.w,bB.x,bB.y,bB.z,bB.w};
        float cv[8] = {cA.x,cA.y,cA.z,cA.w,cB.x,cB.y,cB.z,cB.w};
        float du = dtv*uv;
        float y = uv*Dv;
        #pragma unroll
        for (int n = 0; n < 8; n++){
            float a = __expf(dtv*Av[n]);
            h[n] = a*h[n] + du*bv[n];
            y += h[n]*cv[n];
        }
        float zv = bf2f(*zp);
        y *= zv * sigf(zv);
        dty[ro] = f2bf(y);
        ro += rostep; bp += bpstep; zp += zpstep;
    }
}

// ---------------------------------------------------------------- out_proj MFMA + diff + LN + add x + LN + T-store
// 32-row tiles, grid (384,2) = 768 blocks (3 blocks/CU)
__global__ __launch_bounds__(256,4) void k_final(const unsigned short* __restrict__ y,
    const unsigned short* __restrict__ owb, const float* __restrict__ x, const float* __restrict__ lamp,
    const float* __restrict__ sw, const float* __restrict__ sb,
    const float* __restrict__ n2w, const float* __restrict__ n2b, float* __restrict__ outp)
{
    __shared__ __align__(16) char smem[27264];
    unsigned short* Ast = (unsigned short*)smem;             // phase 1: [2*32][KP] = 16896 B
    float* yt            = (float*)smem;                     // phase 2: [32][129] f32 = 16512 B
    unsigned short* xtb  = (unsigned short*)(smem + 16512);  // [32][132] bf16 = 8448 B
    float* red1          = (float*)(smem + 24960);           // 1024 B
    float* red2          = (float*)(smem + 25984);           // 1024 B
    float* stt           = (float*)(smem + 27008);           //  256 B
    const int bb = blockIdx.y;
    const int l0 = blockIdx.x * 32;                  // grid.x = 384
    const int tid = threadIdx.x;
    const float lam = *lamp;
    #pragma unroll
    for (int p = 0; p < 4; p++){
        int idx = p*256 + tid; int mm = idx >> 9; int li = (idx >> 4) & 31; int g = (idx & 15)*8;
        uint4 vf = *(const uint4*)&y[(((size_t)(mm*2+0)*NB + bb)*LSEQ + l0 + li)*DIMC + g];
        uint4 vb = *(const uint4*)&y[(((size_t)(mm*2+1)*NB + bb)*LSEQ + l0 + li)*DIMC + g];
        const unsigned short* uf = (const unsigned short*)&vf;
        const unsigned short* ub = (const unsigned short*)&vb;
        unsigned short o[8];
        #pragma unroll
        for (int j = 0; j < 8; j++) o[j] = f2bf(bf2f(uf[j]) + bf2f(ub[j]));
        *(uint2*)&Ast[(mm*32 + li)*KP + g]     = *(uint2*)&o[0];
        *(uint2*)&Ast[(mm*32 + li)*KP + g + 4] = *(uint2*)&o[4];
    }
    __syncthreads();
    const int lane = tid & 63, w = tid >> 6;
    const int m15 = lane & 15, q = lane >> 4;
    const int mi = w >> 1;                           // inst (bimamba)
    const int rt = w & 1;                            // 16-row half
    f4_t zf = {0.f,0.f,0.f,0.f};
    f4_t acc[8];
    #pragma unroll
    for (int j = 0; j < 8; j++) acc[j] = zf;
    #pragma unroll
    for (int ks = 0; ks < 4; ks++){
        int k0 = ks*32 + q*8;
        bf16x8 a = ld_frag8(&Ast[(mi*32 + rt*16 + m15)*KP + k0]);
        #pragma unroll
        for (int nt = 0; nt < 8; nt++){
            bf16x8 b = ld_frag16g(&owb[((size_t)mi*DIMC + nt*16 + m15)*DIMC + k0]);
            acc[nt] = __builtin_amdgcn_mfma_f32_16x16x32_bf16(a, b, acc[nt], 0,0,0);
        }
    }
    __syncthreads();                                 // Ast dead
    if (mi == 0){
        #pragma unroll
        for (int nt = 0; nt < 8; nt++){
            int row = rt*16 + q*4;
            int col = nt*16 + m15;
            #pragma unroll
            for (int i = 0; i < 4; i++)
                yt[(row+i)*129 + col] = acc[nt][i];
        }
    }
    {
        const int li = tid & 31, cg = tid >> 5;
        #pragma unroll
        for (int p = 0; p < 16; p++){
            int c = p*8 + cg;
            xtb[li*132 + c] = f2bf(x[(size_t)bb*DIMC*LSEQ + (size_t)c*LSEQ + l0 + li]);
        }
    }
    __syncthreads();
    if (mi == 1){
        #pragma unroll
        for (int nt = 0; nt < 8; nt++){
            int row = rt*16 + q*4;
            int col = nt*16 + m15;
            #pragma unroll
            for (int i = 0; i < 4; i++)
                yt[(row+i)*129 + col] -= lam*acc[nt][i];
        }
    }
    __syncthreads();
    const int r = tid & 31, g = tid >> 5;            // 8 groups of 16 cols
    float s = 0.f, s2 = 0.f;
    #pragma unroll
    for (int k = 0; k < 16; k++){ float v = yt[r*129 + g*16 + k]; s += v; s2 += v*v; }
    red1[g*32 + r] = s; red2[g*32 + r] = s2;
    __syncthreads();
    if (tid < 32){
        float ss = 0.f, ss2 = 0.f;
        #pragma unroll
        for (int gg = 0; gg < 8; gg++){ ss += red1[gg*32 + tid]; ss2 += red2[gg*32 + tid]; }
        float mu = ss*(1.f/128.f);
        float var = ss2*(1.f/128.f) - mu*mu;
        stt[tid*2] = mu; stt[tid*2+1] = rsqrtf(var + EPSV);
    }
    __syncthreads();
    float mu1 = stt[r*2], rs1 = stt[r*2+1];
    s = 0.f; s2 = 0.f;
    #pragma unroll
    for (int k = 0; k < 16; k++){
        int c = g*16 + k;
        float v = (yt[r*129+c] - mu1)*rs1*sw[c] + sb[c] + bf2f(xtb[r*132+c]);
        yt[r*129+c] = v;
        s += v; s2 += v*v;
    }
    __syncthreads();
    red1[g*32 + r] = s; red2[g*32 + r] = s2;
    __syncthreads();
    if (tid < 32){
        float ss = 0.f, ss2 = 0.f;
        #pragma unroll
        for (int gg = 0; gg < 8; gg++){ ss += red1[gg*32 + tid]; ss2 += red2[gg*32 + tid]; }
        float mu = ss*(1.f/128.f);
        float var = ss2*(1.f/128.f) - mu*mu;
        stt[tid*2] = mu; stt[tid*2+1] = rsqrtf(var + EPSV);
    }
    __syncthreads();
    float mu2 = stt[r*2], rs2 = stt[r*2+1];
    #pragma unroll
    for (int k = 0; k < 16; k++){
        int c = g*16 + k;
        float o = (yt[r*129+c] - mu2)*rs2*n2w[c] + n2b[c];
        outp[(size_t)bb*DIMC*LSEQ + (size_t)c*LSEQ + l0 + r] = o;
    }
}

// ----------------------------------------------------------------
extern "C" void kernel_launch(void* const* d_in, const int* in_sizes, int n_in,
                              void* d_out, int out_size, void* d_ws, size_t ws_size,
                              hipStream_t stream)
{
    const float* x    = (const float*)d_in[0];
    const float* n1w  = (const float*)d_in[1];
    const float* n1b  = (const float*)d_in[2];
    const float* n2w  = (const float*)d_in[3];
    const float* n2b  = (const float*)d_in[4];
    const float* slw  = (const float*)d_in[5];
    const float* slb  = (const float*)d_in[6];
    const float* lq   = (const float*)d_in[7];
    const float* wi   = (const float*)d_in[8];
    const float* cw   = (const float*)d_in[9];
    const float* cb   = (const float*)d_in[10];
    const float* xpw  = (const float*)d_in[11];
    const float* dtw  = (const float*)d_in[12];
    const float* dtb  = (const float*)d_in[13];
    const float* alog = (const float*)d_in[14];
    const float* dvec = (const float*)d_in[15];
    const float* ow   = (const float*)d_in[16];

    float* ws = (float*)d_ws;
    unsigned short* xn    = (unsigned short*)(ws);             // 1,572,864 f
    unsigned short* xz    = (unsigned short*)(ws + 1572864);   // 6,291,456 f
    unsigned short* xc    = (unsigned short*)(ws + 7864320);   // 6,291,456 f
    unsigned short* dty   = (unsigned short*)(ws + 14155776);  // 6,291,456 f
    float*          bcb   = ws + 20447232;                     // 1,572,864 f
    float*          st1   = ws + 22020096;                     // 8,388,608 f (8*NCH*128*16)
    unsigned short* wallb = (unsigned short*)(ws + 30408704);  //    36,864 f
    unsigned short* wib   = (unsigned short*)(ws + 30445568);  //    32,768 f
    unsigned short* owb   = (unsigned short*)(ws + 30478336);  //    16,384 f
    float*          lam   = ws + 30494720;                     //         1

    k_wall  <<<dim3(4,144), 128, 0, stream>>>(dtw, xpw, lq, wallb, lam);
    k_prep  <<<96, 256, 0, stream>>>(wi, ow, wib, owb);
    k_normT <<<768, 256, 0, stream>>>(x, n1w, n1b, xn);
    k_inproj<<<dim3(192, 4), 256, 0, stream>>>(xn, wib, xz);
    k_conv  <<<2*NB*(LSEQ/64), 256, 0, stream>>>(xz, cw, cb, xc);
    k_xproj <<<dim3(96, 8), 256, 0, stream>>>(xc, wallb, dtb, dty, bcb);
    k_scan1 <<<8*NCH, 128, 0, stream>>>(dty, xc, bcb, alog, st1);
    k_scan2 <<<32, 256, 0, stream>>>(st1);
    k_scan3 <<<8*NCH, 128, 0, stream>>>(dty, xc, bcb, xz, st1, alog, dvec);
    k_final <<<dim3(384, 2), 256, 0, stream>>>(dty, owb, x, lam, slw, slb, n2w, n2b, (float*)d_out);
}

// Round 13
// 279.153 us; speedup vs baseline: 1.0571x; 1.0571x over previous
//
#include <hip/hip_runtime.h>
#include <math.h>

#define DIMC 128
#define LSEQ 12288
#define NB 2
#define BLR 24576   // NB*LSEQ
#define EPSV 1e-5f
#define NCH 384     // scan chunks per row (3072 blocks -> 24 waves/CU cap)
#define LC 32       // chunk length (NCH*LC = LSEQ)
#define KP 132      // LDS row pad (ushorts) for MFMA staging

typedef __bf16 bf16x8 __attribute__((ext_vector_type(8)));
typedef __attribute__((ext_vector_type(4))) float f4_t;

__device__ __forceinline__ float sigf(float x){ return 1.f/(1.f+__expf(-x)); }
__device__ __forceinline__ float softplusf(float x){
    return fmaxf(x,0.f) + __logf(1.f + __expf(-fabsf(x)));
}
__device__ __forceinline__ float bf2f(unsigned short u){
    union { unsigned int i; float f; } v; v.i = ((unsigned int)u) << 16; return v.f;
}
__device__ __forceinline__ unsigned short f2bf(float f){
    union { float f; unsigned int i; } v; v.f = f;
    unsigned int b = v.i + 0x7FFFu + ((v.i >> 16) & 1u);
    return (unsigned short)(b >> 16);
}
__device__ __forceinline__ bf16x8 ld_frag8(const unsigned short* p){   // 8B-aligned LDS
    union { uint2 u[2]; bf16x8 v; } r;
    r.u[0] = *(const uint2*)(p);
    r.u[1] = *(const uint2*)(p+4);
    return r.v;
}
__device__ __forceinline__ bf16x8 ld_frag16g(const unsigned short* p){ // 16B-aligned global
    union { uint4 u; bf16x8 v; } r; r.u = *(const uint4*)p; return r.v;
}

// ---------------------------------------------------------------- W_all[inst][144][128] (bf16) + lam
__global__ void k_wall(const float* __restrict__ dtw, const float* __restrict__ xpw,
                       const float* __restrict__ lq,
                       unsigned short* __restrict__ wallb, float* __restrict__ lam){
    int inst = blockIdx.x, j = blockIdx.y, k = threadIdx.x;  // grid (4,144), block 128
    const float* xp = xpw + (size_t)inst*24*128;
    float v;
    if (j < 128){
        const float* dw = dtw + (size_t)inst*128*8 + (size_t)j*8;
        v = 0.f;
        #pragma unroll
        for (int r = 0; r < 8; r++) v += dw[r]*xp[r*128 + k];
    } else {
        v = xp[(8 + (j-128))*128 + k];
    }
    wallb[((size_t)inst*144 + j)*128 + k] = f2bf(v);
    if (inst == 0 && j == 0 && k < 64){
        float s = lq[k] + lq[k+64];
        for (int m = 32; m; m >>= 1) s += __shfl_xor(s, m);
        if (k == 0) *lam = 1.f/(1.f+__expf(-s));
    }
}

// ---------------------------------------------------------------- wi, ow -> bf16
__global__ __launch_bounds__(256) void k_prep(const float* __restrict__ wi, const float* __restrict__ ow,
    unsigned short* __restrict__ wib, unsigned short* __restrict__ owb){
    int idx = (blockIdx.x*256 + threadIdx.x)*4;   // grid 96 -> 98304 elems
    const float* src; unsigned short* dst; int off;
    if (idx < 65536){ src = wi;  dst = wib; off = idx; }
    else            { src = ow;  dst = owb; off = idx - 65536; }
    float4 v = *(const float4*)&src[off];
    ushort4 o; o.x=f2bf(v.x); o.y=f2bf(v.y); o.z=f2bf(v.z); o.w=f2bf(v.w);
    *(ushort4*)&dst[off] = o;
}

// ---------------------------------------------------------------- LN1 (stats fused) + transpose -> xn bf16 [b*l][128]
// 64-row tiles; grid MUST be 384 (bb = blockIdx.x/192 in 0..1)
__global__ __launch_bounds__(256) void k_normT(const float* __restrict__ x,
    const float* __restrict__ w1, const float* __restrict__ b1, unsigned short* __restrict__ xn)
{
    __shared__ float t[64*129];
    __shared__ float red1[256], red2[256];
    __shared__ float stt[128];
    const int bb = blockIdx.x / 192;
    const int l0 = (blockIdx.x % 192) * 64;
    const int tid = threadIdx.x;
    const int li = tid & 63, cg = tid >> 6;
    #pragma unroll
    for (int p = 0; p < 32; p++){
        int c = p*4 + cg;
        t[li*129 + c] = x[(size_t)bb*DIMC*LSEQ + (size_t)c*LSEQ + l0 + li];
    }
    __syncthreads();
    {
        int r = tid >> 2, qg = tid & 3;
        float s = 0.f, s2 = 0.f;
        #pragma unroll
        for (int j = 0; j < 32; j++){ float v = t[r*129 + qg*32 + j]; s += v; s2 += v*v; }
        red1[qg*64 + r] = s; red2[qg*64 + r] = s2;
    }
    __syncthreads();
    if (tid < 64){
        float s = 0.f, s2 = 0.f;
        #pragma unroll
        for (int g = 0; g < 4; g++){ s += red1[g*64 + tid]; s2 += red2[g*64 + tid]; }
        float mu = s*(1.f/128.f);
        float var = s2*(1.f/128.f) - mu*mu;
        stt[tid*2] = mu; stt[tid*2+1] = rsqrtf(var + EPSV);
    }
    __syncthreads();
    const int c2 = (tid & 63)*2, lg = tid >> 6;
    #pragma unroll
    for (int p = 0; p < 16; p++){
        int l = p*4 + lg;
        float mu = stt[l*2], rs = stt[l*2+1];
        float v0 = (t[l*129 + c2    ] - mu)*rs*w1[c2    ] + b1[c2    ];
        float v1 = (t[l*129 + c2 + 1] - mu)*rs*w1[c2 + 1] + b1[c2 + 1];
        unsigned int o = (unsigned int)f2bf(v0) | ((unsigned int)f2bf(v1) << 16);
        *(unsigned int*)&xn[(size_t)(bb*LSEQ + l0 + l)*DIMC + c2] = o;
    }
}

// ---------------------------------------------------------------- in_proj MFMA: [128m x 128n x 128k] tiles
__global__ __launch_bounds__(256,4) void k_inproj(const unsigned short* __restrict__ xn,
    const unsigned short* __restrict__ wib, unsigned short* __restrict__ xz)
{
    __shared__ __align__(16) unsigned short As[128*KP];   // 33792 B
    const int row0 = blockIdx.x * 128;   // grid.x = 192
    const int j0   = blockIdx.y * 128;   // grid.y = 4
    const int tid = threadIdx.x;
    #pragma unroll
    for (int p = 0; p < 8; p++){
        int idx = p*256 + tid; int li = idx >> 4; int g = (idx & 15)*8;
        uint4 va = *(const uint4*)&xn[(size_t)(row0+li)*DIMC + g];
        *(uint2*)&As[li*KP + g]     = make_uint2(va.x, va.y);
        *(uint2*)&As[li*KP + g + 4] = make_uint2(va.z, va.w);
    }
    __syncthreads();
    const int lane = tid & 63, w = tid >> 6;
    const int m15 = lane & 15, q = lane >> 4;
    f4_t zf = {0.f,0.f,0.f,0.f};
    f4_t acc[2][8];
    #pragma unroll
    for (int i = 0; i < 2; i++)
        #pragma unroll
        for (int j = 0; j < 8; j++) acc[i][j] = zf;
    #pragma unroll
    for (int ks = 0; ks < 4; ks++){
        int k0 = ks*32 + q*8;
        bf16x8 a0 = ld_frag8(&As[(w*32      + m15)*KP + k0]);
        bf16x8 a1 = ld_frag8(&As[(w*32 + 16 + m15)*KP + k0]);
        #pragma unroll
        for (int nt = 0; nt < 8; nt++){
            bf16x8 b = ld_frag16g(&wib[(size_t)(j0 + nt*16 + m15)*DIMC + k0]);
            acc[0][nt] = __builtin_amdgcn_mfma_f32_16x16x32_bf16(a0, b, acc[0][nt], 0,0,0);
            acc[1][nt] = __builtin_amdgcn_mfma_f32_16x16x32_bf16(a1, b, acc[1][nt], 0,0,0);
        }
    }
    __syncthreads();
    unsigned short* ep = As;             // reuse
    #pragma unroll
    for (int mi = 0; mi < 2; mi++)
        #pragma unroll
        for (int nt = 0; nt < 8; nt++){
            int row = w*32 + mi*16 + q*4;
            int col = nt*16 + m15;
            #pragma unroll
            for (int i = 0; i < 4; i++)
                ep[(row+i)*KP + col] = f2bf(acc[mi][nt][i]);
        }
    __syncthreads();
    #pragma unroll
    for (int p = 0; p < 8; p++){
        int idx = p*256 + tid; int li = idx >> 4; int g = (idx & 15)*8;
        uint2 u0 = *(const uint2*)&ep[li*KP + g];
        uint2 u1 = *(const uint2*)&ep[li*KP + g + 4];
        uint4 o; o.x=u0.x; o.y=u0.y; o.z=u1.x; o.w=u1.y;
        *(uint4*)&xz[(size_t)(row0+li)*512 + j0 + g] = o;
    }
}

// ---------------------------------------------------------------- conv (both directions) + silu
__global__ __launch_bounds__(256) void k_conv(const unsigned short* __restrict__ xz,
    const float* __restrict__ cw, const float* __restrict__ cb, unsigned short* __restrict__ xc)
{
    __shared__ unsigned short tile[70][144];
    const int bid = blockIdx.x;                // grid = 2*2*192
    const int lt = bid % 192;
    const int bb = (bid/192) % NB;
    const int m  = bid / (192*NB);
    const int l0 = lt * 64;
    const int tid = threadIdx.x;
    for (int idx = tid; idx < 70*16; idx += 256){
        int r = idx >> 4, cq = idx & 15;
        int l = l0 - 3 + r;
        uint4 v = make_uint4(0,0,0,0);
        if (l >= 0 && l < LSEQ)
            v = *(const uint4*)&xz[((size_t)(bb*LSEQ + l))*512 + m*256 + cq*8];
        *(uint4*)&tile[r][cq*8] = v;
    }
    __syncthreads();
    const int dimi = tid & 127, lg = tid >> 7;
    float w0a[4], w1a[4];
    #pragma unroll
    for (int k = 0; k < 4; k++){
        w0a[k] = cw[((size_t)(m*2+0)*DIMC + dimi)*4 + k];
        w1a[k] = cw[((size_t)(m*2+1)*DIMC + dimi)*4 + k];
    }
    const float b0 = cb[(m*2+0)*DIMC + dimi];
    const float b1v = cb[(m*2+1)*DIMC + dimi];
    for (int p = 0; p < 32; p++){
        int li = p*2 + lg;
        float t0 = bf2f(tile[li  ][dimi]);
        float t1 = bf2f(tile[li+1][dimi]);
        float t2 = bf2f(tile[li+2][dimi]);
        float t3 = bf2f(tile[li+3][dimi]);
        float t4 = bf2f(tile[li+4][dimi]);
        float t5 = bf2f(tile[li+5][dimi]);
        float t6 = bf2f(tile[li+6][dimi]);
        float v0 = b0  + w0a[0]*t0 + w0a[1]*t1 + w0a[2]*t2 + w0a[3]*t3;
        float v1 = b1v + w1a[3]*t3 + w1a[2]*t4 + w1a[1]*t5 + w1a[0]*t6;
        v0 = v0 * sigf(v0);
        v1 = v1 * sigf(v1);
        xc[(((size_t)(m*2+0)*NB + bb)*LSEQ + l0 + li)*DIMC + dimi] = f2bf(v0);
        xc[(((size_t)(m*2+1)*NB + bb)*LSEQ + l0 + li)*DIMC + dimi] = f2bf(v1);
    }
}

// ---------------------------------------------------------------- x_proj MFMA: [128m x 144n x 128k] per ib
__global__ __launch_bounds__(256,4) void k_xproj(const unsigned short* __restrict__ xc,
    const unsigned short* __restrict__ wallb, const float* __restrict__ dtb,
    unsigned short* __restrict__ dty, float* __restrict__ bcb)
{
    __shared__ __align__(16) unsigned short As[128*KP];   // 33792 B
    const int row0 = blockIdx.x * 128;   // grid.x = 96
    const int ib   = blockIdx.y;         // 0..7
    const int inst = ib >> 1;
    const int tid = threadIdx.x;
    const size_t abase = (size_t)ib * LSEQ * DIMC;
    #pragma unroll
    for (int p = 0; p < 8; p++){
        int idx = p*256 + tid; int li = idx >> 4; int g = (idx & 15)*8;
        uint4 va = *(const uint4*)&xc[abase + (size_t)(row0+li)*DIMC + g];
        *(uint2*)&As[li*KP + g]     = make_uint2(va.x, va.y);
        *(uint2*)&As[li*KP + g + 4] = make_uint2(va.z, va.w);
    }
    __syncthreads();
    const int lane = tid & 63, w = tid >> 6;
    const int m15 = lane & 15, q = lane >> 4;
    f4_t zf = {0.f,0.f,0.f,0.f};
    f4_t acc[2][9];
    #pragma unroll
    for (int i = 0; i < 2; i++)
        #pragma unroll
        for (int j = 0; j < 9; j++) acc[i][j] = zf;
    #pragma unroll
    for (int ks = 0; ks < 4; ks++){
        int k0 = ks*32 + q*8;
        bf16x8 a0 = ld_frag8(&As[(w*32      + m15)*KP + k0]);
        bf16x8 a1 = ld_frag8(&As[(w*32 + 16 + m15)*KP + k0]);
        #pragma unroll
        for (int nt = 0; nt < 9; nt++){
            bf16x8 b = ld_frag16g(&wallb[((size_t)inst*144 + nt*16 + m15)*DIMC + k0]);
            acc[0][nt] = __builtin_amdgcn_mfma_f32_16x16x32_bf16(a0, b, acc[0][nt], 0,0,0);
            acc[1][nt] = __builtin_amdgcn_mfma_f32_16x16x32_bf16(a1, b, acc[1][nt], 0,0,0);
        }
    }
    #pragma unroll
    for (int mi = 0; mi < 2; mi++){
        int row = w*32 + mi*16 + q*4;
        #pragma unroll
        for (int i = 0; i < 4; i++)
            bcb[((size_t)ib*LSEQ + row0 + row + i)*16 + m15] = acc[mi][8][i];
    }
    __syncthreads();
    unsigned short* ep = As;             // dt bf16 [128][KP]
    #pragma unroll
    for (int nt = 0; nt < 8; nt++){
        int col = nt*16 + m15;
        float bias = dtb[inst*DIMC + col];
        #pragma unroll
        for (int mi = 0; mi < 2; mi++){
            int row = w*32 + mi*16 + q*4;
            #pragma unroll
            for (int i = 0; i < 4; i++)
                ep[(row+i)*KP + col] = f2bf(softplusf(acc[mi][nt][i] + bias));
        }
    }
    __syncthreads();
    #pragma unroll
    for (int p = 0; p < 8; p++){
        int idx = p*256 + tid; int li = idx >> 4; int g = (idx & 15)*8;
        uint2 u0 = *(const uint2*)&ep[li*KP + g];
        uint2 u1 = *(const uint2*)&ep[li*KP + g + 4];
        uint4 o; o.x=u0.x; o.y=u0.y; o.z=u1.x; o.w=u1.y;
        *(uint4*)&dty[abase + (size_t)(row0+li)*DIMC + g] = o;
    }
}

// ---------------------------------------------------------------- scan S1 (per-chunk reduce)
__global__ __launch_bounds__(128) void k_scan1(const unsigned short* __restrict__ dt,
    const unsigned short* __restrict__ xc, const float* __restrict__ bcb,
    const float* __restrict__ alog, float* __restrict__ st)
{
    const int ib = blockIdx.x & 7;
    const int c  = blockIdx.x >> 3;            // 0..NCH-1
    const int inst = ib >> 1;
    const int d = inst & 1;
    const int tid = threadIdx.x;
    float Av[8];
    #pragma unroll
    for (int n = 0; n < 8; n++)
        Av[n] = -__expf(alog[((size_t)inst*DIMC + tid)*8 + n]);
    const size_t rbase = (size_t)ib*LSEQ*DIMC;
    float Ac[8], Bc[8];
    #pragma unroll
    for (int n = 0; n < 8; n++){ Ac[n] = 1.f; Bc[n] = 0.f; }
    #pragma unroll 8
    for (int s = 0; s < LC; s++){
        int j = c*LC + s;
        int l = d ? (LSEQ-1-j) : j;
        size_t ro = rbase + (size_t)l*DIMC + tid;
        float dtv = bf2f(dt[ro]);
        float uv  = bf2f(xc[ro]);
        const float* bp = bcb + ((size_t)ib*LSEQ + l)*16;
        float4 bA = *(const float4*)bp;
        float4 bB = *(const float4*)(bp+4);
        float bv[8] = {bA.x,bA.y,bA.z,bA.w,bB.x,bB.y,bB.z,bB.w};
        float du = dtv*uv;
        #pragma unroll
        for (int n = 0; n < 8; n++){
            float a = __expf(dtv*Av[n]);
            Bc[n] = a*Bc[n] + du*bv[n];
            Ac[n] *= a;
        }
    }
    float* so = st + (((size_t)ib*NCH + c)*DIMC + tid)*16;
    #pragma unroll
    for (int n = 0; n < 8; n++){ so[n] = Ac[n]; so[8+n] = Bc[n]; }
}

// ---------------------------------------------------------------- scan S2 (cross-chunk exclusive prefix, in-place)
__global__ __launch_bounds__(256) void k_scan2(float* __restrict__ st){
    int gid = blockIdx.x*256 + threadIdx.x;    // 8192 threads
    int ib = gid >> 10;
    int r  = gid & 1023;
    int dim = r >> 3, n = r & 7;
    float Bp = 0.f;
    for (int c = 0; c < NCH; c++){
        size_t o = (((size_t)ib*NCH + c)*DIMC + dim)*16;
        float A = st[o+n], Bv = st[o+8+n];
        st[o+n] = Bp;
        Bp = A*Bp + Bv;
    }
}

// ---------------------------------------------------------------- scan S3 (replay, y in place over dt)
__global__ __launch_bounds__(128) void k_scan3(unsigned short* __restrict__ dty,
    const unsigned short* __restrict__ xc, const float* __restrict__ bcb,
    const unsigned short* __restrict__ xz, const float* __restrict__ st,
    const float* __restrict__ alog, const float* __restrict__ dvec)
{
    const int ib = blockIdx.x & 7;
    const int c  = blockIdx.x >> 3;
    const int inst = ib >> 1, bb = ib & 1;
    const int m = inst >> 1, d = inst & 1;
    const int tid = threadIdx.x;
    float Av[8];
    #pragma unroll
    for (int n = 0; n < 8; n++)
        Av[n] = -__expf(alog[((size_t)inst*DIMC + tid)*8 + n]);
    const float Dv = dvec[inst*DIMC + tid];
    float h[8];
    const float* hp = st + (((size_t)ib*NCH + c)*DIMC + tid)*16;
    #pragma unroll
    for (int n = 0; n < 8; n++) h[n] = hp[n];
    const size_t rbase = (size_t)ib*LSEQ*DIMC;
    const size_t zbase = (size_t)bb*LSEQ*512 + m*256 + 128;
    #pragma unroll 8
    for (int s = 0; s < LC; s++){
        int j = c*LC + s;
        int l = d ? (LSEQ-1-j) : j;
        size_t ro = rbase + (size_t)l*DIMC + tid;
        float dtv = bf2f(dty[ro]);
        float uv  = bf2f(xc[ro]);
        const float* bp = bcb + ((size_t)ib*LSEQ + l)*16;
        float4 bA = *(const float4*)bp;
        float4 bB = *(const float4*)(bp+4);
        float4 cA = *(const float4*)(bp+8);
        float4 cB = *(const float4*)(bp+12);
        float bv[8] = {bA.x,bA.y,bA.z,bA.w,bB.x,bB.y,bB.z,bB.w};
        float cv[8] = {cA.x,cA.y,cA.z,cA.w,cB.x,cB.y,cB.z,cB.w};
        float du = dtv*uv;
        float y = uv*Dv;
        #pragma unroll
        for (int n = 0; n < 8; n++){
            float a = __expf(dtv*Av[n]);
            h[n] = a*h[n] + du*bv[n];
            y += h[n]*cv[n];
        }
        float zv = bf2f(xz[zbase + (size_t)l*512 + tid]);
        y *= zv * sigf(zv);
        dty[ro] = f2bf(y);
    }
}

// ---------------------------------------------------------------- out_proj MFMA + diff + LN + add x + LN + T-store
__global__ __launch_bounds__(256,3) void k_final(const unsigned short* __restrict__ y,
    const unsigned short* __restrict__ owb, const float* __restrict__ x, const float* __restrict__ lamp,
    const float* __restrict__ sw, const float* __restrict__ sb,
    const float* __restrict__ n2w, const float* __restrict__ n2b, float* __restrict__ outp)
{
    __shared__ __align__(16) char smem[52480];
    unsigned short* Ast = (unsigned short*)smem;             // phase 1: [2*64][KP] = 33792 B
    float* yt            = (float*)smem;                     // phase 2: [64][129] f32 = 33024 B
    unsigned short* xtb  = (unsigned short*)(smem + 33024);  // [64][132] bf16 = 16896 B
    float* red1          = (float*)(smem + 49920);
    float* red2          = (float*)(smem + 50944);
    float* stt           = (float*)(smem + 51968);
    const int bb = blockIdx.y;
    const int l0 = blockIdx.x * 64;                  // grid.x = 192
    const int tid = threadIdx.x;
    const float lam = *lamp;
    #pragma unroll
    for (int p = 0; p < 8; p++){
        int idx = p*256 + tid; int mm = idx >> 10; int li = (idx >> 4) & 63; int g = (idx & 15)*8;
        uint4 vf = *(const uint4*)&y[(((size_t)(mm*2+0)*NB + bb)*LSEQ + l0 + li)*DIMC + g];
        uint4 vb = *(const uint4*)&y[(((size_t)(mm*2+1)*NB + bb)*LSEQ + l0 + li)*DIMC + g];
        const unsigned short* uf = (const unsigned short*)&vf;
        const unsigned short* ub = (const unsigned short*)&vb;
        unsigned short o[8];
        #pragma unroll
        for (int j = 0; j < 8; j++) o[j] = f2bf(bf2f(uf[j]) + bf2f(ub[j]));
        *(uint2*)&Ast[(mm*64 + li)*KP + g]     = *(uint2*)&o[0];
        *(uint2*)&Ast[(mm*64 + li)*KP + g + 4] = *(uint2*)&o[4];
    }
    __syncthreads();
    const int lane = tid & 63, w = tid >> 6;
    const int m15 = lane & 15, q = lane >> 4;
    f4_t zf = {0.f,0.f,0.f,0.f};
    f4_t acc[2][8];
    #pragma unroll
    for (int i = 0; i < 2; i++)
        #pragma unroll
        for (int j = 0; j < 8; j++) acc[i][j] = zf;
    #pragma unroll
    for (int ks = 0; ks < 4; ks++){
        int k0 = ks*32 + q*8;
        bf16x8 a0 = ld_frag8(&Ast[(       w*16 + m15)*KP + k0]);
        bf16x8 a1 = ld_frag8(&Ast[(64   + w*16 + m15)*KP + k0]);
        #pragma unroll
        for (int nt = 0; nt < 8; nt++){
            bf16x8 b0 = ld_frag16g(&owb[((size_t)0*DIMC + nt*16 + m15)*DIMC + k0]);
            bf16x8 b1 = ld_frag16g(&owb[((size_t)1*DIMC + nt*16 + m15)*DIMC + k0]);
            acc[0][nt] = __builtin_amdgcn_mfma_f32_16x16x32_bf16(a0, b0, acc[0][nt], 0,0,0);
            acc[1][nt] = __builtin_amdgcn_mfma_f32_16x16x32_bf16(a1, b1, acc[1][nt], 0,0,0);
        }
    }
    __syncthreads();
    #pragma unroll
    for (int nt = 0; nt < 8; nt++){
        int row = w*16 + q*4;
        int col = nt*16 + m15;
        #pragma unroll
        for (int i = 0; i < 4; i++)
            yt[(row+i)*129 + col] = acc[0][nt][i] - lam*acc[1][nt][i];
    }
    {
        const int li = tid & 63, cg = tid >> 6;
        #pragma unroll
        for (int p = 0; p < 32; p++){
            int c = p*4 + cg;
            xtb[li*132 + c] = f2bf(x[(size_t)bb*DIMC*LSEQ + (size_t)c*LSEQ + l0 + li]);
        }
    }
    __syncthreads();
    const int r = tid & 63, g = tid >> 6;
    float s = 0.f, s2 = 0.f;
    #pragma unroll
    for (int k = 0; k < 32; k++){ float v = yt[r*129 + g*32 + k]; s += v; s2 += v*v; }
    red1[g*64 + r] = s; red2[g*64 + r] = s2;
    __syncthreads();
    if (tid < 64){
        float ss = 0.f, ss2 = 0.f;
        #pragma unroll
        for (int gg = 0; gg < 4; gg++){ ss += red1[gg*64 + tid]; ss2 += red2[gg*64 + tid]; }
        float mu = ss*(1.f/128.f);
        float var = ss2*(1.f/128.f) - mu*mu;
        stt[tid*2] = mu; stt[tid*2+1] = rsqrtf(var + EPSV);
    }
    __syncthreads();
    float mu1 = stt[r*2], rs1 = stt[r*2+1];
    s = 0.f; s2 = 0.f;
    #pragma unroll
    for (int k = 0; k < 32; k++){
        int c = g*32 + k;
        float v = (yt[r*129+c] - mu1)*rs1*sw[c] + sb[c] + bf2f(xtb[r*132+c]);
        yt[r*129+c] = v;
        s += v; s2 += v*v;
    }
    __syncthreads();
    red1[g*64 + r] = s; red2[g*64 + r] = s2;
    __syncthreads();
    if (tid < 64){
        float ss = 0.f, ss2 = 0.f;
        #pragma unroll
        for (int gg = 0; gg < 4; gg++){ ss += red1[gg*64 + tid]; ss2 += red2[gg*64 + tid]; }
        float mu = ss*(1.f/128.f);
        float var = ss2*(1.f/128.f) - mu*mu;
        stt[tid*2] = mu; stt[tid*2+1] = rsqrtf(var + EPSV);
    }
    __syncthreads();
    float mu2 = stt[r*2], rs2 = stt[r*2+1];
    #pragma unroll
    for (int k = 0; k < 32; k++){
        int c = g*32 + k;
        float o = (yt[r*129+c] - mu2)*rs2*n2w[c] + n2b[c];
        outp[(size_t)bb*DIMC*LSEQ + (size_t)c*LSEQ + l0 + r] = o;
    }
}

// ----------------------------------------------------------------
extern "C" void kernel_launch(void* const* d_in, const int* in_sizes, int n_in,
                              void* d_out, int out_size, void* d_ws, size_t ws_size,
                              hipStream_t stream)
{
    const float* x    = (const float*)d_in[0];
    const float* n1w  = (const float*)d_in[1];
    const float* n1b  = (const float*)d_in[2];
    const float* n2w  = (const float*)d_in[3];
    const float* n2b  = (const float*)d_in[4];
    const float* slw  = (const float*)d_in[5];
    const float* slb  = (const float*)d_in[6];
    const float* lq   = (const float*)d_in[7];
    const float* wi   = (const float*)d_in[8];
    const float* cw   = (const float*)d_in[9];
    const float* cb   = (const float*)d_in[10];
    const float* xpw  = (const float*)d_in[11];
    const float* dtw  = (const float*)d_in[12];
    const float* dtb  = (const float*)d_in[13];
    const float* alog = (const float*)d_in[14];
    const float* dvec = (const float*)d_in[15];
    const float* ow   = (const float*)d_in[16];

    float* ws = (float*)d_ws;
    unsigned short* xn    = (unsigned short*)(ws);             // 1,572,864 f
    unsigned short* xz    = (unsigned short*)(ws + 1572864);   // 6,291,456 f
    unsigned short* xc    = (unsigned short*)(ws + 7864320);   // 6,291,456 f
    unsigned short* dty   = (unsigned short*)(ws + 14155776);  // 6,291,456 f
    float*          bcb   = ws + 20447232;                     // 1,572,864 f
    float*          st1   = ws + 22020096;                     // 6,291,456 f (8*NCH*128*16)
    unsigned short* wallb = (unsigned short*)(ws + 28311552);  //    36,864 f
    unsigned short* wib   = (unsigned short*)(ws + 28348416);  //    32,768 f
    unsigned short* owb   = (unsigned short*)(ws + 28381184);  //    16,384 f
    float*          lam   = ws + 28397568;                     //         1

    k_wall  <<<dim3(4,144), 128, 0, stream>>>(dtw, xpw, lq, wallb, lam);
    k_prep  <<<96, 256, 0, stream>>>(wi, ow, wib, owb);
    k_normT <<<384, 256, 0, stream>>>(x, n1w, n1b, xn);
    k_inproj<<<dim3(192, 4), 256, 0, stream>>>(xn, wib, xz);
    k_conv  <<<2*NB*(LSEQ/64), 256, 0, stream>>>(xz, cw, cb, xc);
    k_xproj <<<dim3(96, 8), 256, 0, stream>>>(xc, wallb, dtb, dty, bcb);
    k_scan1 <<<8*NCH, 128, 0, stream>>>(dty, xc, bcb, alog, st1);
    k_scan2 <<<32, 256, 0, stream>>>(st1);
    k_scan3 <<<8*NCH, 128, 0, stream>>>(dty, xc, bcb, xz, st1, alog, dvec);
    k_final <<<dim3(192, 2), 256, 0, stream>>>(dty, owb, x, lam, slw, slb, n2w, n2b, (float*)d_out);
}